// Round 6
// baseline (83.126 us; speedup 1.0000x reference)
//
#include <hip/hip_runtime.h>

// Problem constants
#define NMOLS   256
#define NATOMS  32
#define REPD    256
#define NPCAS   128
#define NSTACKS 32
#define NFEAT   4096
#define NELEM   4

// ws layout (bytes)
#define LIST_OFF 0          // int list[8192]
#define META_OFF 32768      // int meta[16]
#define SUB_OFF  40960      // float sub[8192*128]

#define SCALE_C 0.029462782549439476f   // sqrt(128)/(3*128)
#define FEATN_C 0.022097086912079608f   // sqrt(2/4096)

__device__ __forceinline__ int elem_of(int z) {
  return (z == 1) ? 0 : (z == 6) ? 1 : (z == 7) ? 2 : (z == 8) ? 3 : -1;
}

// ---------------- K0: bucket atoms by element (deterministic), zero out ----------------
__global__ __launch_bounds__(256) void k0_bucket(const int* __restrict__ Z,
                                                 int* __restrict__ list,
                                                 int* __restrict__ meta,
                                                 float* __restrict__ out) {
  __shared__ int4 cntS[256];
  const int t = threadIdx.x;
  out[t] = 0.0f;
  int c0 = 0, c1 = 0, c2 = 0, c3 = 0;
  #pragma unroll
  for (int k = 0; k < 32; ++k) {
    const int z = Z[k * 256 + t];
    c0 += (z == 1); c1 += (z == 6); c2 += (z == 7); c3 += (z == 8);
  }
  int4 v = make_int4(c0, c1, c2, c3);
  cntS[t] = v;
  __syncthreads();
  for (int step = 1; step < 256; step <<= 1) {
    int4 add = make_int4(0, 0, 0, 0);
    if (t >= step) add = cntS[t - step];
    __syncthreads();
    v.x += add.x; v.y += add.y; v.z += add.z; v.w += add.w;
    cntS[t] = v;
    __syncthreads();
  }
  const int4 tot = cntS[255];
  int o0 = v.x - c0;
  int o1 = tot.x + v.y - c1;
  int o2 = tot.x + tot.y + v.z - c2;
  int o3 = tot.x + tot.y + tot.z + v.w - c3;
  #pragma unroll
  for (int k = 0; k < 32; ++k) {
    const int a = k * 256 + t;
    const int z = Z[a];
    if      (z == 1) list[o0++] = a;
    else if (z == 6) list[o1++] = a;
    else if (z == 7) list[o2++] = a;
    else if (z == 8) list[o3++] = a;
  }
  if (t == 0) {
    meta[0] = tot.x; meta[1] = tot.y; meta[2] = tot.z; meta[3] = tot.w;
    meta[4] = 0;
    meta[5] = tot.x;
    meta[6] = tot.x + tot.y;
    meta[7] = tot.x + tot.y + tot.z;
    meta[8] = tot.x + tot.y + tot.z + tot.w;
  }
}

// ---------------- K1: register-tiled matvec (verbatim R3 verified version) ----------------
__global__ __launch_bounds__(256) void k1_matvec(const float* __restrict__ rep,
                                                 const float* __restrict__ reductors,
                                                 const int* __restrict__ list,
                                                 const int* __restrict__ meta,
                                                 float* __restrict__ sub) {
  const int e = blockIdx.y;
  const int cnt = meta[e];
  const int off = meta[4 + e];
  const int start = blockIdx.x * 64;
  if (start >= cnt) return;
  const int n = min(64, cnt - start);
  const int t = threadIdx.x;

  __shared__ int aidS[64];
  __shared__ float repS[64][128];     // 32 KB, one K-half at a time

  if (t < 64) aidS[t] = list[off + start + (t < n ? t : 0)];

  const int pq = t & 31, jq = t >> 5;
  const int p0 = pq * 4, j0 = jq * 8;
  const float* red_e = reductors + e * (REPD * NPCAS);

  float acc[8][4];
  #pragma unroll
  for (int j = 0; j < 8; ++j)
    #pragma unroll
    for (int q = 0; q < 4; ++q) acc[j][q] = 0.0f;

  for (int kh = 0; kh < 2; ++kh) {
    __syncthreads();
    #pragma unroll
    for (int it = 0; it < 8; ++it) {
      const int idx = it * 256 + t;
      const int row = idx >> 5;          // 32 quads per row
      const int q   = idx & 31;
      *(float4*)&repS[row][q * 4] =
          *(const float4*)(rep + (size_t)aidS[row] * 256 + kh * 128 + q * 4);
    }
    __syncthreads();

    const float* redk = red_e + (kh * 128) * 128 + p0;
    for (int r0 = 0; r0 < 128; r0 += 4) {
      const float4 rv0 = *(const float4*)(redk + (r0 + 0) * 128);
      const float4 rv1 = *(const float4*)(redk + (r0 + 1) * 128);
      const float4 rv2 = *(const float4*)(redk + (r0 + 2) * 128);
      const float4 rv3 = *(const float4*)(redk + (r0 + 3) * 128);
      float4 rp[8];
      #pragma unroll
      for (int j = 0; j < 8; ++j)
        rp[j] = *(const float4*)&repS[j0 + j][r0];
      #pragma unroll
      for (int j = 0; j < 8; ++j) {
        acc[j][0] = fmaf(rp[j].w, rv3.x, fmaf(rp[j].z, rv2.x, fmaf(rp[j].y, rv1.x, fmaf(rp[j].x, rv0.x, acc[j][0]))));
        acc[j][1] = fmaf(rp[j].w, rv3.y, fmaf(rp[j].z, rv2.y, fmaf(rp[j].y, rv1.y, fmaf(rp[j].x, rv0.y, acc[j][1]))));
        acc[j][2] = fmaf(rp[j].w, rv3.z, fmaf(rp[j].z, rv2.z, fmaf(rp[j].y, rv1.z, fmaf(rp[j].x, rv0.z, acc[j][2]))));
        acc[j][3] = fmaf(rp[j].w, rv3.w, fmaf(rp[j].z, rv2.w, fmaf(rp[j].y, rv1.w, fmaf(rp[j].x, rv0.w, acc[j][3]))));
      }
    }
  }

  #pragma unroll
  for (int j = 0; j < 8; ++j) {
    const int a = j0 + j;
    if (a < n) {
      float4 v = make_float4(acc[j][0], acc[j][1], acc[j][2], acc[j][3]);
      *(float4*)(sub + (size_t)(off + start + a) * 128 + p0) = v;
    }
  }
}

// ---------------- K2: R3 structure, ONLY change = 4 chains/wave instead of 2 ----------------
template <int CTRL>
__device__ __forceinline__ float dppx(float x) {
  return __int_as_float(__builtin_amdgcn_update_dpp(0, __float_as_int(x), CTRL, 0xF, 0xF, true));
}
template <int OFF>
__device__ __forceinline__ float swzx(float x) {
  return __int_as_float(__builtin_amdgcn_ds_swizzle(__float_as_int(x), OFF));
}

#define BFLY_DPP(x, CTRL, sg) { float t_ = dppx<CTRL>(x); (x) = fmaf((x), (sg), t_); }
#define BFLY_SWZ(x, OFF, sg)  { float t_ = swzx<OFF>(x);  (x) = fmaf((x), (sg), t_); }

#define SWAP16(a, b) asm("v_permlane16_swap_b32 %0, %1" : "+v"(a), "+v"(b));
#define SWAP32(a, b) asm("v_permlane32_swap_b32 %0, %1" : "+v"(a), "+v"(b));
#define XST16(lo, hi) { SWAP16(lo, hi) float s_ = (lo) + (hi), d_ = (lo) - (hi); SWAP16(s_, d_) (lo) = s_; (hi) = d_; }
#define XST32(lo, hi) { SWAP32(lo, hi) float s_ = (lo) + (hi), d_ = (lo) - (hi); SWAP32(s_, d_) (lo) = s_; (hi) = d_; }

// xor1: quad_perm 0xB1; xor2: 0x4E; xor4: ds_swizzle; xor8: row_ror:8;
// xor16/xor32: permlane swap trick; bit6: register add/sub.
#define FW128(lo, hi) { \
  { float a_ = (lo) + (hi), b_ = (lo) - (hi); (lo) = a_; (hi) = b_; } \
  BFLY_DPP(lo, 0xB1, sg1)    BFLY_DPP(hi, 0xB1, sg1) \
  BFLY_DPP(lo, 0x4E, sg2)    BFLY_DPP(hi, 0x4E, sg2) \
  BFLY_SWZ(lo, 0x101F, sg4)  BFLY_SWZ(hi, 0x101F, sg4) \
  BFLY_DPP(lo, 0x128, sg8)   BFLY_DPP(hi, 0x128, sg8) \
  XST16(lo, hi) \
  XST32(lo, hi) }

__global__ __launch_bounds__(256) void k2_features(const float* __restrict__ sub,
                                                   const int* __restrict__ list,
                                                   const int* __restrict__ meta,
                                                   const int* __restrict__ Z,
                                                   const float* __restrict__ Dmat,
                                                   const float* __restrict__ bias,
                                                   const float* __restrict__ alpha,
                                                   float* __restrict__ out) {
  const int total = meta[8];
  const int w = threadIdx.x >> 6, lane = threadIdx.x & 63;
  const int pos0 = blockIdx.x * 16 + w * 4;
  if (pos0 >= total) return;
  const bool has1 = (pos0 + 1) < total;
  const bool has2 = (pos0 + 2) < total;
  const bool has3 = (pos0 + 3) < total;

  const float sg1 = (lane & 1) ? -1.0f : 1.0f;
  const float sg2 = (lane & 2) ? -1.0f : 1.0f;
  const float sg4 = (lane & 4) ? -1.0f : 1.0f;
  const float sg8 = (lane & 8) ? -1.0f : 1.0f;

  const int aid0 = list[pos0];
  const int e0 = elem_of(Z[aid0]);
  const float slo0 = sub[(size_t)pos0 * 128 + lane];
  const float shi0 = sub[(size_t)pos0 * 128 + 64 + lane];

  int aid1 = aid0, e1 = 0; float slo1 = 0.0f, shi1 = 0.0f;
  if (has1) {
    aid1 = list[pos0 + 1]; e1 = elem_of(Z[aid1]);
    slo1 = sub[(size_t)(pos0 + 1) * 128 + lane];
    shi1 = sub[(size_t)(pos0 + 1) * 128 + 64 + lane];
  }
  int aid2 = aid0, e2 = 0; float slo2 = 0.0f, shi2 = 0.0f;
  if (has2) {
    aid2 = list[pos0 + 2]; e2 = elem_of(Z[aid2]);
    slo2 = sub[(size_t)(pos0 + 2) * 128 + lane];
    shi2 = sub[(size_t)(pos0 + 2) * 128 + 64 + lane];
  }
  int aid3 = aid0, e3 = 0; float slo3 = 0.0f, shi3 = 0.0f;
  if (has3) {
    aid3 = list[pos0 + 3]; e3 = elem_of(Z[aid3]);
    slo3 = sub[(size_t)(pos0 + 3) * 128 + lane];
    shi3 = sub[(size_t)(pos0 + 3) * 128 + 64 + lane];
  }

  const float* De0 = Dmat + e0 * (2 * NSTACKS * NPCAS);
  const float* De1 = Dmat + e1 * (2 * NSTACKS * NPCAS);
  const float* De2 = Dmat + e2 * (2 * NSTACKS * NPCAS);
  const float* De3 = Dmat + e3 * (2 * NSTACKS * NPCAS);
  const float* be0 = bias + e0 * NFEAT;
  const float* be1 = bias + e1 * NFEAT;
  const float* be2 = bias + e2 * NFEAT;
  const float* be3 = bias + e3 * NFEAT;

  float acc0 = 0.0f, acc1 = 0.0f, acc2 = 0.0f, acc3 = 0.0f;

  for (int s = 0; s < NSTACKS; ++s) {
    const int s0 = s * 128, s1 = (NSTACKS + s) * 128;
    const float alo = alpha[s0 + lane], ahi = alpha[s0 + 64 + lane];

    float lo0 = slo0 * De0[s0 + lane], hi0 = shi0 * De0[s0 + 64 + lane];
    float lo1 = slo1 * De1[s0 + lane], hi1 = shi1 * De1[s0 + 64 + lane];
    float lo2 = slo2 * De2[s0 + lane], hi2 = shi2 * De2[s0 + 64 + lane];
    float lo3 = slo3 * De3[s0 + lane], hi3 = shi3 * De3[s0 + 64 + lane];

    FW128(lo0, hi0) FW128(lo1, hi1) FW128(lo2, hi2) FW128(lo3, hi3)

    lo0 *= De0[s1 + lane]; hi0 *= De0[s1 + 64 + lane];
    lo1 *= De1[s1 + lane]; hi1 *= De1[s1 + 64 + lane];
    lo2 *= De2[s1 + lane]; hi2 *= De2[s1 + 64 + lane];
    lo3 *= De3[s1 + lane]; hi3 *= De3[s1 + 64 + lane];

    FW128(lo0, hi0) FW128(lo1, hi1) FW128(lo2, hi2) FW128(lo3, hi3)

    acc0 = fmaf(__cosf(fmaf(lo0, SCALE_C, be0[s0 + lane])),      alo, acc0);
    acc0 = fmaf(__cosf(fmaf(hi0, SCALE_C, be0[s0 + 64 + lane])), ahi, acc0);
    acc1 = fmaf(__cosf(fmaf(lo1, SCALE_C, be1[s0 + lane])),      alo, acc1);
    acc1 = fmaf(__cosf(fmaf(hi1, SCALE_C, be1[s0 + 64 + lane])), ahi, acc1);
    acc2 = fmaf(__cosf(fmaf(lo2, SCALE_C, be2[s0 + lane])),      alo, acc2);
    acc2 = fmaf(__cosf(fmaf(hi2, SCALE_C, be2[s0 + 64 + lane])), ahi, acc2);
    acc3 = fmaf(__cosf(fmaf(lo3, SCALE_C, be3[s0 + lane])),      alo, acc3);
    acc3 = fmaf(__cosf(fmaf(hi3, SCALE_C, be3[s0 + 64 + lane])), ahi, acc3);
  }

  #pragma unroll
  for (int o = 32; o > 0; o >>= 1) {
    acc0 += __shfl_xor(acc0, o, 64);
    acc1 += __shfl_xor(acc1, o, 64);
    acc2 += __shfl_xor(acc2, o, 64);
    acc3 += __shfl_xor(acc3, o, 64);
  }
  if (lane == 0)         atomicAdd(out + (aid0 >> 5), acc0 * FEATN_C);
  if (lane == 1 && has1) atomicAdd(out + (aid1 >> 5), acc1 * FEATN_C);
  if (lane == 2 && has2) atomicAdd(out + (aid2 >> 5), acc2 * FEATN_C);
  if (lane == 3 && has3) atomicAdd(out + (aid3 >> 5), acc3 * FEATN_C);
}

extern "C" void kernel_launch(void* const* d_in, const int* in_sizes, int n_in,
                              void* d_out, int out_size, void* d_ws, size_t ws_size,
                              hipStream_t stream) {
  const float* rep       = (const float*)d_in[0];
  const int*   Z         = (const int*)  d_in[1];
  const float* reductors = (const float*)d_in[2];
  const float* Dmat      = (const float*)d_in[3];
  const float* bias      = (const float*)d_in[4];
  const float* alpha     = (const float*)d_in[5];
  float* out = (float*)d_out;

  char* wsb = (char*)d_ws;
  int*   list = (int*)(wsb + LIST_OFF);
  int*   meta = (int*)(wsb + META_OFF);
  float* sub  = (float*)(wsb + SUB_OFF);

  k0_bucket<<<1, 256, 0, stream>>>(Z, list, meta, out);
  dim3 g1(32, 4);                        // 64-atom tiles (verified R3 config)
  k1_matvec<<<g1, 256, 0, stream>>>(rep, reductors, list, meta, sub);
  k2_features<<<512, 256, 0, stream>>>(sub, list, meta, Z, Dmat, bias, alpha, out);
}